// Round 12
// baseline (324.130 us; speedup 1.0000x reference)
//
#include <hip/hip_runtime.h>
#include <math.h>

#define B    32
#define S    2048
#define D    512
#define H    512
#define NP   8
#define NSL  32     // hid-slices per step kernel
#define HSL  16     // hid per slice
#define NBT  8      // batch groups
#define BG   4      // batches per group
#define NCH  8      // attn chunks per batch
#define SCHUNK 256

__device__ __forceinline__ float sigmoidf_(float x) {
  return 1.0f / (1.0f + __expf(-x));
}

__device__ __forceinline__ unsigned bf16rne(float x) {
  unsigned v = __float_as_uint(x);
  return (v + 0x7fffu + ((v >> 16) & 1u)) >> 16;
}

// ---------------- convert enc -> bf16 (RNE), packed 2-per-uint32 ----------------
// 33.55M floats; thread converts 8. grid 16384 x 256.
__global__ __launch_bounds__(256)
void k_initE(const float* __restrict__ enc, unsigned short* __restrict__ encH) {
  const size_t i = ((size_t)blockIdx.x * 256 + threadIdx.x) * 8;
  const float4 a = *(const float4*)(enc + i);
  const float4 b = *(const float4*)(enc + i + 4);
  uint4 o;
  o.x = bf16rne(a.x) | (bf16rne(a.y) << 16);
  o.y = bf16rne(a.z) | (bf16rne(a.w) << 16);
  o.z = bf16rne(b.x) | (bf16rne(b.y) << 16);
  o.w = bf16rne(b.z) | (bf16rne(b.w) << 16);
  *(uint4*)(encH + i) = o;
}

// ---------------- init: Wt = [W_ih | W_hh]^T (Wt[k][j]), states, num_sent ----------------
__global__ __launch_bounds__(256)
void k_init(const float* __restrict__ W_ih, const float* __restrict__ W_hh,
            const float* __restrict__ init_h, const float* __restrict__ init_c,
            const float* __restrict__ init_in, const int* __restrict__ ns_raw,
            float* __restrict__ Wt, float* __restrict__ hbuf, float* __restrict__ cbuf,
            float* __restrict__ xin0, int* __restrict__ ns) {
  __shared__ float tbuf[64][65];
  const int blk = blockIdx.x, tid = threadIdx.x;
  const int jt = blk & 31, kt = blk >> 5;        // 32 j-tiles x 16 k-tiles of 64x64
  const int j0 = jt * 64, k0 = kt * 64;
  const int r0 = tid >> 6, cc = tid & 63;
  for (int rr = r0; rr < 64; rr += 4) {
    int j = j0 + rr, k = k0 + cc;
    tbuf[rr][cc] = (k < 512) ? W_ih[(size_t)j * 512 + k]
                             : W_hh[(size_t)j * 512 + (k - 512)];
  }
  __syncthreads();
  for (int rr = r0; rr < 64; rr += 4)
    Wt[(size_t)(k0 + rr) * 2048 + j0 + cc] = tbuf[cc][rr];

  int idx = blk * 256 + tid;
  if (idx < B * H) {
    int d = idx & 511;
    hbuf[idx] = init_h[d];   // buffer 0
    cbuf[idx] = init_c[d];
    xin0[idx] = init_in[d];
  }
  if (idx == 0) {
    // num_sent >= 1 always. If int64 (LE), high word of elem 0 (raw[1]) is 0.
    bool is64 = (ns_raw[1] == 0);
    for (int i = 0; i < B; ++i) ns[i] = is64 ? ns_raw[2 * i] : ns_raw[i];
  }
}

// ---------------- fused step kernel (identical to round 11) ----------------
// grid 256 = (sl: 32 hid-slices) x (bg: 8 groups of 4 batches), 512 threads.
__global__ __launch_bounds__(512, 1)
void k_step(const float* __restrict__ xin0, const float* __restrict__ bih,
            const float* __restrict__ bhh, const float* __restrict__ Wq,
            const float* __restrict__ scW, const float* __restrict__ scb,
            const float* __restrict__ Wt,
            const float* __restrict__ ch_m, const float* __restrict__ ch_l,
            const float* __restrict__ ch_o,
            float* __restrict__ hbuf, float* __restrict__ cbuf,
            float* __restrict__ qpart, float* __restrict__ out, int t) {
  __shared__ float X[BG][1024];       // 16 KB: [xin | h(t-1)] per batch
  __shared__ float gacc[8][64][5];    // 10 KB (pad 5)
  __shared__ float gl[4][16][BG];     // gate values
  __shared__ float hl[BG][16];        // h slice for qpart
  __shared__ float sred[8][BG];       // score partials [wave][b]

  const int tid = threadIdx.x;
  const int sl = blockIdx.x >> 3;     // 0..31
  const int bg = blockIdx.x & 7;      // 0..7
  const int b0 = bg * BG;

  // ---- phase A ----
  if (t == 0) {
    #pragma unroll
    for (int bl = 0; bl < BG; ++bl)
      X[bl][tid] = xin0[(b0 + bl) * 512 + tid];
  } else {
    const float swd = scW[tid];
    #pragma unroll
    for (int bl = 0; bl < BG; ++bl) {
      const int b = b0 + bl;
      float M = -1e30f;
      #pragma unroll
      for (int c = 0; c < NCH; ++c) M = fmaxf(M, ch_m[b * NCH + c]);
      float e[NCH]; float L = 0.f;
      #pragma unroll
      for (int c = 0; c < NCH; ++c) {
        e[c] = __expf(ch_m[b * NCH + c] - M);
        L += ch_l[b * NCH + c] * e[c];
      }
      float v = 0.f;
      #pragma unroll
      for (int c = 0; c < NCH; ++c)
        v += ch_o[((size_t)(b * NCH + c)) * 512 + tid] * e[c];
      v *= (1.0f / L);
      X[bl][tid] = v;
      float p = v * swd;
      #pragma unroll
      for (int off = 32; off > 0; off >>= 1) p += __shfl_xor(p, off);
      if ((tid & 63) == 0) sred[tid >> 6][bl] = p;
    }
  }
  // copy h(t-1) into X[.][512..1023]: 4 batches x 128 float4 = 512 float4
  if (t < NP) {
    const float4* hsrc = (const float4*)(hbuf + (t & 1) * (B * 512));
    int bl = tid >> 7;
    int off = tid & 127;
    float4 hv = hsrc[(b0 + bl) * 128 + off];
    *(float4*)&X[bl][512 + off * 4] = hv;
  }
  __syncthreads();

  if (t >= 1 && tid < BG) {
    float s = 0.f;
    #pragma unroll
    for (int w = 0; w < 8; ++w) s += sred[w][tid];
    if (sl == 0) out[(t - 1) * B + b0 + tid] = s + scb[0];
  }
  if (t >= NP) return;   // t==8: final-score-only call

  // ---- phase B: gates ----
  {
    const int jloc = tid & 63;              // (gi, ho)
    const int kc = tid >> 6;                // wave id = k-chunk
    const int gi = jloc >> 4, ho = jloc & 15;
    const int jg = gi * 512 + sl * HSL + ho;
    const int k0c = kc * 128;
    const float* wp = Wt + (size_t)k0c * 2048 + jg;
    float acc[BG] = {0, 0, 0, 0};
    for (int kk = 0; kk < 32; ++kk) {
      float wv0 = wp[(size_t)(kk * 4 + 0) * 2048];
      float wv1 = wp[(size_t)(kk * 4 + 1) * 2048];
      float wv2 = wp[(size_t)(kk * 4 + 2) * 2048];
      float wv3 = wp[(size_t)(kk * 4 + 3) * 2048];
      #pragma unroll
      for (int bl = 0; bl < BG; ++bl) {
        const float4 xv = *(const float4*)&X[bl][k0c + kk * 4];  // LDS broadcast
        acc[bl] += wv0 * xv.x + wv1 * xv.y + wv2 * xv.z + wv3 * xv.w;
      }
    }
    #pragma unroll
    for (int bl = 0; bl < BG; ++bl) gacc[kc][jloc][bl] = acc[bl];
  }
  __syncthreads();

  // ---- kc-reduce + bias -> gl (256 threads: 4 bl x 64 jloc) ----
  if (tid < 256) {
    const int bl = tid >> 6, jloc = tid & 63;
    const int gi = jloc >> 4, ho = jloc & 15;
    const int jg = gi * 512 + sl * HSL + ho;
    float g = bih[jg] + bhh[jg];
    #pragma unroll
    for (int kc = 0; kc < 8; ++kc) g += gacc[kc][jloc][bl];
    gl[gi][ho][bl] = g;
  }
  __syncthreads();

  // ---- LSTM cell (64 threads: 4 bl x 16 ho) ----
  if (tid < BG * HSL) {
    const int ho = tid & 15, bl = tid >> 4;
    const int bglob = b0 + bl, hid = sl * HSL + ho;
    float i_ = sigmoidf_(gl[0][ho][bl]);
    float f_ = sigmoidf_(gl[1][ho][bl]);
    float g_ = tanhf(gl[2][ho][bl]);
    float o_ = sigmoidf_(gl[3][ho][bl]);
    float cv = cbuf[bglob * 512 + hid];          // unique owner (sl,bg)
    float cn = f_ * cv + i_ * g_;
    cbuf[bglob * 512 + hid] = cn;
    float hv = o_ * tanhf(cn);
    hbuf[((t + 1) & 1) * (B * 512) + bglob * 512 + hid] = hv;
    hl[bl][ho] = hv;
  }
  __syncthreads();

  // ---- q-partials: qpart[sl][b][d] = sum_{ho} h[b][sl*16+ho] * Wq[sl*16+ho][d] ----
  {
    float w[HSL];
    #pragma unroll
    for (int ho = 0; ho < HSL; ++ho)
      w[ho] = Wq[(size_t)(sl * HSL + ho) * 512 + tid];
    #pragma unroll
    for (int bl = 0; bl < BG; ++bl) {
      float acc = 0.f;
      #pragma unroll
      for (int ho = 0; ho < HSL; ++ho) acc += hl[bl][ho] * w[ho];
      qpart[((size_t)sl * B + b0 + bl) * 512 + tid] = acc;
    }
  }
}

// ---------------- attn on bf16 enc: q = sum(qpart), one-pass online softmax ----------------
// grid 256 = (b: 32) x (ch: 8), 512 threads = 8 waves; pairwise rows + 1-pair prefetch.
// Each row = 512 bf16 = 1 KB; one uint4 (8 bf16) per lane covers the row.
__global__ __launch_bounds__(512, 1)
void k_attn(const unsigned short* __restrict__ encH, const float* __restrict__ qpart,
            const int* __restrict__ ns_buf, float* __restrict__ ch_m,
            float* __restrict__ ch_l, float* __restrict__ ch_o) {
  __shared__ float q_lds[512];
  __shared__ float wm[8], wl[8];
  __shared__ float wo[8][512];
  const int b  = blockIdx.x >> 3;
  const int ch = blockIdx.x & 7;
  const int tid = threadIdx.x;
  const int lane = tid & 63;
  const int wv = tid >> 6;

  // q = sum over 32 slices
  {
    float s = 0.f;
    #pragma unroll 8
    for (int sl = 0; sl < NSL; ++sl)
      s += qpart[((size_t)sl * B + b) * 512 + tid];
    q_lds[tid] = s;
  }
  __syncthreads();

  const float4 qa  = *(const float4*)&q_lds[lane * 8];
  const float4 qb4 = *(const float4*)&q_lds[lane * 8 + 4];

  const int s0 = ch * SCHUNK;
  const int nsb = ns_buf[b];
  float m = -1e30f, l = 0.f;
  float o0=0,o1=0,o2=0,o3=0,o4=0,o5=0,o6=0,o7=0;

  const int send = min(s0 + SCHUNK, nsb);
  const size_t rowbase = (size_t)b * S;

#define CVT2(u, e0, e1) { (e0) = __uint_as_float((u) << 16); (e1) = __uint_as_float((u) & 0xffff0000u); }

  int r = s0 + 2 * wv;
  if (r < send) {
    bool has1 = (r + 1 < send);
    uint4 ua = *(const uint4*)(encH + (rowbase + r) * 512 + lane * 8);
    uint4 uc = *(const uint4*)(encH + (rowbase + (has1 ? r + 1 : r)) * 512 + lane * 8);
    while (true) {
      const int rn = r + 16;
      const bool hasn = (rn < send);
      uint4 nua, nuc;
      bool nhas1 = false;
      if (hasn) {
        nhas1 = (rn + 1 < send);
        nua = *(const uint4*)(encH + (rowbase + rn) * 512 + lane * 8);
        nuc = *(const uint4*)(encH + (rowbase + (nhas1 ? rn + 1 : rn)) * 512 + lane * 8);
      }
      float a0,a1,a2,a3,a4,a5,a6,a7, c0,c1,c2,c3,c4,c5,c6,c7;
      CVT2(ua.x, a0, a1); CVT2(ua.y, a2, a3); CVT2(ua.z, a4, a5); CVT2(ua.w, a6, a7);
      CVT2(uc.x, c0, c1); CVT2(uc.y, c2, c3); CVT2(uc.z, c4, c5); CVT2(uc.w, c6, c7);
      float d0 = qa.x*a0 + qa.y*a1 + qa.z*a2 + qa.w*a3
               + qb4.x*a4 + qb4.y*a5 + qb4.z*a6 + qb4.w*a7;
      float d1 = qa.x*c0 + qa.y*c1 + qa.z*c2 + qa.w*c3
               + qb4.x*c4 + qb4.y*c5 + qb4.z*c6 + qb4.w*c7;
      #pragma unroll
      for (int off = 32; off > 0; off >>= 1) {
        d0 += __shfl_xor(d0, off);
        d1 += __shfl_xor(d1, off);
      }
      if (!has1) d1 = -1e30f;            // wave-uniform
      float nm = fmaxf(m, fmaxf(d0, d1));
      float sc = __expf(m - nm);
      float w0 = __expf(d0 - nm);
      float w1 = __expf(d1 - nm);        // 0 when pair's 2nd row invalid
      l = l * sc + w0 + w1;
      o0 = o0*sc + w0*a0 + w1*c0; o1 = o1*sc + w0*a1 + w1*c1;
      o2 = o2*sc + w0*a2 + w1*c2; o3 = o3*sc + w0*a3 + w1*c3;
      o4 = o4*sc + w0*a4 + w1*c4; o5 = o5*sc + w0*a5 + w1*c5;
      o6 = o6*sc + w0*a6 + w1*c6; o7 = o7*sc + w0*a7 + w1*c7;
      m = nm;
      if (!hasn) break;
      r = rn; has1 = nhas1;
      ua = nua; uc = nuc;
    }
  }
#undef CVT2
  if (lane == 0) { wm[wv] = m; wl[wv] = l; }
  float4* wop = (float4*)&wo[wv][lane * 8];
  wop[0] = make_float4(o0, o1, o2, o3);
  wop[1] = make_float4(o4, o5, o6, o7);
  __syncthreads();

  float M = wm[0];
  #pragma unroll
  for (int w = 1; w < 8; ++w) M = fmaxf(M, wm[w]);
  float e[8]; float L = 0.f;
  #pragma unroll
  for (int w = 0; w < 8; ++w) { e[w] = __expf(wm[w] - M); L += wl[w] * e[w]; }
  if (tid == 0) { ch_m[b * NCH + ch] = M; ch_l[b * NCH + ch] = L; }
  float v = 0.f;
  #pragma unroll
  for (int w = 0; w < 8; ++w) v += wo[w][tid] * e[w];
  ch_o[((size_t)(b * NCH + ch)) * 512 + tid] = v;
}

extern "C" void kernel_launch(void* const* d_in, const int* in_sizes, int n_in,
                              void* d_out, int out_size, void* d_ws, size_t ws_size,
                              hipStream_t stream) {
  const float* enc     = (const float*)d_in[0];
  const int*   ns_raw  = (const int*)d_in[1];
  // d_in[2] = num_pred (8)
  const float* init_h  = (const float*)d_in[3];
  const float* init_c  = (const float*)d_in[4];
  const float* init_in = (const float*)d_in[5];
  const float* W_ih    = (const float*)d_in[6];
  const float* W_hh    = (const float*)d_in[7];
  const float* b_ih    = (const float*)d_in[8];
  const float* b_hh    = (const float*)d_in[9];
  const float* Wq      = (const float*)d_in[10];
  const float* score_W = (const float*)d_in[11];
  const float* score_b = (const float*)d_in[12];
  float* out = (float*)d_out;

  float* ws    = (float*)d_ws;
  float* Wt    = ws;                  // 1024*2048 = 2097152
  float* hbuf  = ws + 2097152;        // 2*B*H = 32768 (double-buffered)
  float* cbuf  = ws + 2129920;        // 16384
  float* xin0  = ws + 2146304;        // 16384
  float* qpart = ws + 2162688;        // NSL*B*512 = 524288
  float* ch_m  = ws + 2686976;        // B*NCH = 256
  float* ch_l  = ws + 2687232;        // 256
  float* ch_o  = ws + 2687488;        // B*NCH*512 = 131072
  int*   ns    = (int*)(ws + 2818560);           // 32 ints
  unsigned short* encH = (unsigned short*)(ws + 2818592);  // 33.55M bf16 = 67 MB

  k_initE<<<16384, 256, 0, stream>>>(enc, encH);
  k_init<<<512, 256, 0, stream>>>(W_ih, W_hh, init_h, init_c, init_in, ns_raw,
                                  Wt, hbuf, cbuf, xin0, ns);
  for (int t = 0; t < NP; ++t) {
    k_step<<<NSL * NBT, 512, 0, stream>>>(xin0, b_ih, b_hh, Wq, score_W, score_b, Wt,
                                          ch_m, ch_l, ch_o, hbuf, cbuf, qpart, out, t);
    k_attn<<<B * NCH, 512, 0, stream>>>(encH, qpart, ns, ch_m, ch_l, ch_o);
  }
  k_step<<<NSL * NBT, 512, 0, stream>>>(xin0, b_ih, b_hh, Wq, score_W, score_b, Wt,
                                        ch_m, ch_l, ch_o, hbuf, cbuf, qpart, out, NP);
}